// Round 11
// baseline (33434.830 us; speedup 1.0000x reference)
//
#include <hip/hip_runtime.h>

// Problem constants (from reference)
#define BB    2048
#define TT    100
#define CC    8
#define HD    64
#define HHD   128
#define OO    10
#define MROWS 8      // batch rows per block; grid = 256 blocks = 1 block/CU
#define NTHR  512    // 8 waves; 128-VGPR budget (r6 proven spill-free envelope)

__device__ __forceinline__ float fast_tanh(float x) {
  float e = __expf(2.0f * x);
  return 1.0f - 2.0f / (e + 1.0f);
}

__global__ void zero_out_k(float* o) {
  if (threadIdx.x < 2) o[threadIdx.x] = 0.0f;
}

__global__ void __launch_bounds__(NTHR)
cde_main(const float* __restrict__ coeffs, const int* __restrict__ yy,
         const float* __restrict__ times,
         const float* __restrict__ W_init, const float* __restrict__ b_init,
         const float* __restrict__ W_in,  const float* __restrict__ b_in,
         const float* __restrict__ W_h,   const float* __restrict__ b_h,
         const float* __restrict__ W_out, const float* __restrict__ b_out,
         const float* __restrict__ W_read,const float* __restrict__ b_read,
         float* __restrict__ out)
{
  __shared__ float sZs[MROWS][HD];        // 2KB   stage-input z
  __shared__ float pA [MROWS][HHD];       // 4KB   bias-primed partials, layer A
  __shared__ float p1 [MROWS][HHD];       // 4KB   hidden1
  __shared__ float p2 [MROWS][HHD];       // 4KB   hidden2
  __shared__ float pB [MROWS][576];       // 18KB  big layer, addr = col + (col>>3)
  __shared__ float sDx[MROWS][CC];
  __shared__ float sLog[MROWS][OO];

  const int t    = threadIdx.x;
  const int wv   = t >> 6;        // wave id 0..7 (k-slice owner; epilogue row)
  const int l    = t & 63;        // lane         (col owner; epilogue h)
  const int row0 = blockIdx.x * MROWS;

  // tiny persistent scalars
  const float binx = b_in[l],      biny = b_in[l + 64];
  const float b1x  = b_h[l],       b1y  = b_h[l + 64];
  const float b2x  = b_h[HHD + l], b2y  = b_h[HHD + l + 64];
  const float bO   = b_out[t];

  // ---- z0 ; wave wv owns (row wv, h=l) RK state ----
  float z0, kacc = 0.f;
  {
    const float* cf = coeffs + (size_t)(row0 + wv) * (TT*CC);
    float a = b_init[l];
#pragma unroll
    for (int c = 0; c < CC; ++c) a = fmaf(cf[c], W_init[c*HD + l], a);
    z0 = a;
    sZs[wv][l] = a;
  }

  // ---- prime partial buffers with bias ----
  pA[wv][l] = binx;  pA[wv][l + 64] = biny;
  p1[wv][l] = b1x;   p1[wv][l + 64] = b1y;
  p2[wv][l] = b2x;   p2[wv][l + 64] = b2y;
#pragma unroll 2
  for (int r = 0; r < MROWS; ++r) pB[r][t + (t >> 3)] = bO;
  __syncthreads();

#pragma unroll 1
  for (int step = 0; step < TT-1; ++step) {
    const float dti = times[step+1] - times[step];
    if (t < MROWS * CC) {   // P5 readers barrier-separated both directions
      const int r = t >> 3, c = t & 7;
      const float* cf = coeffs + (size_t)(row0 + r)*(TT*CC) + step*CC + c;
      sDx[r][c] = (cf[CC] - cf[0]) / dti;
    }

#pragma unroll 1
    for (int s = 0; s < 4; ++s) {
      // Prefetch buffers: issued one phase early, drained by the intervening
      // barrier (s_barrier waits vmcnt(0)) -> latency overlaps prior compute.
      float wh1x[16], wh1y[16];       // W_h layer 1, k in [16wv,16wv+16)
      float wh2x[16], wh2y[16];       // W_h layer 2

      // ---- P1: layer A. k in [8wv,8wv+8), cols (l,l+64). + prefetch wh1, re-prime pB ----
      {
#pragma unroll
        for (int j = 0; j < 16; ++j) {           // PREFETCH wh1 (consumed in P2)
          const float* wr = W_h + (16*wv + j)*HHD;
          wh1x[j] = wr[l];
          wh1y[j] = wr[l + 64];
        }
        const int kb = 8 * wv;
        float wx[8], wy[8];
#pragma unroll
        for (int j = 0; j < 8; ++j) {
          const float* wr = W_in + (kb + j) * HHD;
          wx[j] = wr[l];
          wy[j] = wr[l + 64];
        }
#pragma unroll 2
        for (int r = 0; r < MROWS; ++r) {
          const float4 za = *(const float4*)&sZs[r][kb];       // broadcast
          const float4 zb = *(const float4*)&sZs[r][kb + 4];
          float a0 = 0.f, a1 = 0.f;
          a0 = fmaf(za.x, wx[0], a0); a1 = fmaf(za.x, wy[0], a1);
          a0 = fmaf(za.y, wx[1], a0); a1 = fmaf(za.y, wy[1], a1);
          a0 = fmaf(za.z, wx[2], a0); a1 = fmaf(za.z, wy[2], a1);
          a0 = fmaf(za.w, wx[3], a0); a1 = fmaf(za.w, wy[3], a1);
          a0 = fmaf(zb.x, wx[4], a0); a1 = fmaf(zb.x, wy[4], a1);
          a0 = fmaf(zb.y, wx[5], a0); a1 = fmaf(zb.y, wy[5], a1);
          a0 = fmaf(zb.z, wx[6], a0); a1 = fmaf(zb.z, wy[6], a1);
          a0 = fmaf(zb.w, wx[7], a0); a1 = fmaf(zb.w, wy[7], a1);
          atomicAdd(&pA[r][l],      a0);
          atomicAdd(&pA[r][l + 64], a1);
        }
#pragma unroll 2
        for (int r = 0; r < MROWS; ++r) pB[r][t + (t >> 3)] = bO;
      }
      __syncthreads();
      // ---- P2: hidden1 with prefetched wh1. + prefetch wh2 ----
      {
#pragma unroll
        for (int j = 0; j < 16; ++j) {           // PREFETCH wh2 (consumed in P3)
          const float* wr = W_h + HHD*HHD + (16*wv + j)*HHD;
          wh2x[j] = wr[l];
          wh2y[j] = wr[l + 64];
        }
        const int kb = 16 * wv;
#pragma unroll 2
        for (int r = 0; r < MROWS; ++r) {
          float a0 = 0.f, a1 = 0.f;
#pragma unroll
          for (int c4 = 0; c4 < 4; ++c4) {
            const float4 hv = *(const float4*)&pA[r][kb + 4*c4];   // broadcast
            const float h0 = fmaxf(hv.x, 0.f), h1 = fmaxf(hv.y, 0.f);
            const float h2 = fmaxf(hv.z, 0.f), h3 = fmaxf(hv.w, 0.f);
            a0 = fmaf(h0, wh1x[4*c4+0], a0); a1 = fmaf(h0, wh1y[4*c4+0], a1);
            a0 = fmaf(h1, wh1x[4*c4+1], a0); a1 = fmaf(h1, wh1y[4*c4+1], a1);
            a0 = fmaf(h2, wh1x[4*c4+2], a0); a1 = fmaf(h2, wh1y[4*c4+2], a1);
            a0 = fmaf(h3, wh1x[4*c4+3], a0); a1 = fmaf(h3, wh1y[4*c4+3], a1);
          }
          atomicAdd(&p1[r][l],      a0);
          atomicAdd(&p1[r][l + 64], a1);
        }
      }
      __syncthreads();
      // ---- P3: hidden2 with prefetched wh2. + re-prime pA ----
      {
        const int kb = 16 * wv;
#pragma unroll 2
        for (int r = 0; r < MROWS; ++r) {
          float a0 = 0.f, a1 = 0.f;
#pragma unroll
          for (int c4 = 0; c4 < 4; ++c4) {
            const float4 hv = *(const float4*)&p1[r][kb + 4*c4];   // broadcast
            const float h0 = fmaxf(hv.x, 0.f), h1 = fmaxf(hv.y, 0.f);
            const float h2 = fmaxf(hv.z, 0.f), h3 = fmaxf(hv.w, 0.f);
            a0 = fmaf(h0, wh2x[4*c4+0], a0); a1 = fmaf(h0, wh2y[4*c4+0], a1);
            a0 = fmaf(h1, wh2x[4*c4+1], a0); a1 = fmaf(h1, wh2y[4*c4+1], a1);
            a0 = fmaf(h2, wh2x[4*c4+2], a0); a1 = fmaf(h2, wh2y[4*c4+2], a1);
            a0 = fmaf(h3, wh2x[4*c4+3], a0); a1 = fmaf(h3, wh2y[4*c4+3], a1);
          }
          atomicAdd(&p2[r][l],      a0);
          atomicAdd(&p2[r][l + 64], a1);
        }
        pA[wv][l] = binx;  pA[wv][l + 64] = biny;
      }
      __syncthreads();
      // ---- P4: big layer. k in [16wv,16wv+16), lane cols 8l..8l+7.
      //      kc loop rolled (code size); acc fully unrolled (regs). + re-prime p1 ----
      {
        const int kb = 16 * wv;
        float acc[MROWS][8];
#pragma unroll
        for (int r = 0; r < MROWS; ++r)
#pragma unroll
          for (int c = 0; c < 8; ++c) acc[r][c] = 0.f;

        const float* wp = W_out + (size_t)kb * (HD*CC) + 8*l;
#pragma unroll 1
        for (int kc = 0; kc < 4; ++kc) {      // 4 chunks of 4 k
          float w[4][8];                       // 32 regs, chunk-local
#pragma unroll
          for (int j = 0; j < 4; ++j) {
            const float4 a = *(const float4*)(wp + (4*kc + j)*(HD*CC));      // 2KB/wave
            const float4 b = *(const float4*)(wp + (4*kc + j)*(HD*CC) + 4);
            w[j][0] = a.x; w[j][1] = a.y; w[j][2] = a.z; w[j][3] = a.w;
            w[j][4] = b.x; w[j][5] = b.y; w[j][6] = b.z; w[j][7] = b.w;
          }
#pragma unroll
          for (int r = 0; r < MROWS; ++r) {
            const float4 hv = *(const float4*)&p2[r][kb + 4*kc];   // broadcast
            const float h0 = fmaxf(hv.x, 0.f), h1 = fmaxf(hv.y, 0.f);
            const float h2 = fmaxf(hv.z, 0.f), h3 = fmaxf(hv.w, 0.f);
#pragma unroll
            for (int c = 0; c < 8; ++c) {
              acc[r][c] = fmaf(h0, w[0][c], acc[r][c]);
              acc[r][c] = fmaf(h1, w[1][c], acc[r][c]);
              acc[r][c] = fmaf(h2, w[2][c], acc[r][c]);
              acc[r][c] = fmaf(h3, w[3][c], acc[r][c]);
            }
          }
        }
        // cols 8l..8l+7 -> padded addr 9l..9l+7 (conflict-free)
#pragma unroll 2
        for (int r = 0; r < MROWS; ++r)
#pragma unroll
          for (int c = 0; c < 8; ++c)
            atomicAdd(&pB[r][9*l + c], acc[r][c]);
        p1[wv][l] = b1x;  p1[wv][l + 64] = b1y;
      }
      __syncthreads();
      // ---- P5: epilogue (all 8 waves) + re-prime p2 ----
      {
        const float* pr = &pB[wv][9*l];       // cols 8l..8l+7, conflict-free
        const float u0 = pr[0], u1 = pr[1], u2 = pr[2], u3 = pr[3];
        const float u4 = pr[4], u5 = pr[5], u6 = pr[6], u7 = pr[7];
        const float4 d0 = *(const float4*)&sDx[wv][0];    // broadcast
        const float4 d1 = *(const float4*)&sDx[wv][4];
        float g = fast_tanh(u0)*d0.x + fast_tanh(u1)*d0.y
                + fast_tanh(u2)*d0.z + fast_tanh(u3)*d0.w
                + fast_tanh(u4)*d1.x + fast_tanh(u5)*d1.y
                + fast_tanh(u6)*d1.z + fast_tanh(u7)*d1.w;
        if (s == 0)      kacc = g;
        else if (s == 3) kacc += g;
        else             kacc += 2.0f * g;
        float zs;
        if (s == 3) {
          z0 = z0 + dti * (1.0f/6.0f) * kacc;
          zs = z0;
        } else {
          zs = z0 + ((s == 2) ? dti : 0.5f * dti) * g;
        }
        sZs[wv][l] = zs;
        p2[wv][l] = b2x;  p2[wv][l + 64] = b2y;
      }
      __syncthreads();
    } // stages
  }   // steps

  // ---- readout: logits = zT @ W_read + b_read ; loss + accuracy ----
  if (t < MROWS * OO) {
    const int r = t / OO, o = t % OO;
    float a = b_read[o];
#pragma unroll 8
    for (int k = 0; k < HD; ++k) a = fmaf(sZs[r][k], W_read[k*OO + o], a);
    sLog[r][o] = a;
  }
  __syncthreads();
  if (t < 64) {
    float lv = 0.f, cv = 0.f;
    if (t < MROWS) {
      const int r = t;
      float mx = sLog[r][0]; int am = 0;
#pragma unroll
      for (int o = 1; o < OO; ++o) { const float v = sLog[r][o]; if (v > mx) { mx = v; am = o; } }
      float se = 0.f;
#pragma unroll
      for (int o = 0; o < OO; ++o) se += expf(sLog[r][o] - mx);
      const float lse = mx + logf(se);
      const int yr = yy[row0 + r];
      lv = (lse - sLog[r][yr]) * (1.0f / (float)BB);
      cv = (am == yr) ? 1.0f : 0.0f;
    }
    lv += __shfl_xor(lv, 1); lv += __shfl_xor(lv, 2); lv += __shfl_xor(lv, 4);
    cv += __shfl_xor(cv, 1); cv += __shfl_xor(cv, 2); cv += __shfl_xor(cv, 4);
    if (t == 0) { atomicAdd(&out[0], lv); atomicAdd(&out[1], cv); }
  }
}

extern "C" void kernel_launch(void* const* d_in, const int* in_sizes, int n_in,
                              void* d_out, int out_size, void* d_ws, size_t ws_size,
                              hipStream_t stream) {
  const float* coeffs = (const float*)d_in[0];
  const int*   y      = (const int*)  d_in[1];
  const float* times  = (const float*)d_in[2];
  const float* W_init = (const float*)d_in[3];
  const float* b_init = (const float*)d_in[4];
  const float* W_in   = (const float*)d_in[5];
  const float* b_in   = (const float*)d_in[6];
  const float* W_h    = (const float*)d_in[7];
  const float* b_h    = (const float*)d_in[8];
  const float* W_out  = (const float*)d_in[9];
  const float* b_out  = (const float*)d_in[10];
  const float* W_read = (const float*)d_in[11];
  const float* b_read = (const float*)d_in[12];
  float* out = (float*)d_out;

  zero_out_k<<<1, 64, 0, stream>>>(out);   // d_out is poisoned 0xAA before every replay
  cde_main<<<BB/MROWS, NTHR, 0, stream>>>(coeffs, y, times, W_init, b_init,
                                          W_in, b_in, W_h, b_h, W_out, b_out,
                                          W_read, b_read, out);
}